// Round 3
// baseline (124.871 us; speedup 1.0000x reference)
//
#include <hip/hip_runtime.h>

// CostVolume2D: B=8, H=256, W=512, C=32, n_disp=12, stride=1.
// cost[b,h,w,d] = sum_c |feat_l[b,h,w,c] - feat_r[b,h,w-d,c]|, feat_r zero-padded left.
//
// Block = 256 threads = one full row; thread t owns pixels (2t, 2t+1).
// feat_r row staged in LDS as parity-split SoA planes, in 2 channel-half passes:
//   plane q (chunk = float4 of 4 channels), section parity (col&1), slot idx = col>>1.
//   Read at fixed (q, e): slot = t + const  ->  lanes hit consecutive 16B chunks
//   (conflict-free linear pattern). 6 guard chunks per section absorb t<6 underflow.

constexpr int Wd    = 512;
constexpr int ND    = 12;
constexpr int SECT  = 264;           // 6 guard + 256 idx + 2 pad (16B chunks)
constexpr int PLANE = 2 * SECT;      // 528
constexpr int NCHUNK = 4 * PLANE;    // 2112 chunks = 33 KiB, 33 runs of 64

__device__ __forceinline__ float l1_4(float4 a, float4 b) {
    return fabsf(a.x - b.x) + fabsf(a.y - b.y) + fabsf(a.z - b.z) + fabsf(a.w - b.w);
}

__global__ __launch_bounds__(256) void cost_volume_kernel(
    const float* __restrict__ fl,
    const float* __restrict__ fr,
    float* __restrict__ out)
{
    __shared__ float4 lds4[NCHUNK];

    const int t    = threadIdx.x;            // pixel-pair index in row
    const int wave = t >> 6;
    const int lane = t & 63;
    const int bh   = blockIdx.x;             // b*H + h
    const float* fr_row = fr + (size_t)bh * Wd * 32;

    const size_t pix0 = (size_t)bh * Wd + 2 * t;
    const float4* fl4 = reinterpret_cast<const float4*>(fl);

    float res0[ND], res1[ND];
    #pragma unroll
    for (int d = 0; d < ND; ++d) { res0[d] = 0.f; res1[d] = 0.f; }
    float lsum0 = 0.f, lsum1 = 0.f;

    #pragma unroll
    for (int h = 0; h < 2; ++h) {
        if (h == 1) __syncthreads();         // pass-0 reads done before overwrite

        // ---- stage feat_r (channel half h): linear LDS dest, permuted global src
        #pragma unroll
        for (int it = 0; it < 9; ++it) {
            const int r = it * 4 + wave;
            if (r < 33) {
                const int c      = r * 64 + lane;        // chunk 0..2111
                const int q      = c / PLANE;
                const int pp     = c - q * PLANE;
                const int parity = pp >= SECT;
                const int ii     = pp - parity * SECT;
                int col = 2 * (ii - 6) + parity;         // guard slots -> clamped
                col = min(max(col, 0), Wd - 1);
                const float* src = fr_row + col * 32 + h * 16 + q * 4;
                __builtin_amdgcn_global_load_lds(
                    (const __attribute__((address_space(1))) void*)src,
                    (__attribute__((address_space(3))) void*)(lds4 + c),
                    16, 0, 0);
            }
        }

        // ---- feat_l for both pixels (this channel half) + |L| partials
        float4 L0[4], L1[4];
        #pragma unroll
        for (int qq = 0; qq < 4; ++qq) {
            L0[qq] = fl4[pix0 * 8 + h * 4 + qq];
            L1[qq] = fl4[(pix0 + 1) * 8 + h * 4 + qq];
            lsum0 += fabsf(L0[qq].x) + fabsf(L0[qq].y) + fabsf(L0[qq].z) + fabsf(L0[qq].w);
            lsum1 += fabsf(L1[qq].x) + fabsf(L1[qq].y) + fabsf(L1[qq].z) + fabsf(L1[qq].w);
        }

        __syncthreads();                     // staged tile visible

        // ---- accumulate: 13 window columns serve 24 (pixel,d) pairs per q
        #pragma unroll
        for (int qq = 0; qq < 4; ++qq) {
            const float4 A0 = L0[qq], A1 = L1[qq];
            const int beven = qq * PLANE + 6 + t;
            const int bodd  = beven + SECT;
            #pragma unroll
            for (int ee = 0; ee < 13; ++ee) {
                const int e      = ee - 11;              // col = 2t + e
                const int parity = e & 1;
                const int fe     = (e - parity) / 2;     // floor(e/2)
                const float4 rv  = lds4[(parity ? bodd : beven) + fe];
                if (e <= 0)   res0[-e]    += l1_4(A0, rv);   // d0 = -e
                if (e >= -10) res1[1 - e] += l1_4(A1, rv);   // d1 = 1-e
            }
        }
    }

    // ---- left edge: w < d -> feat_r fully shifted out (zeros) -> sum|feat_l|
    const int w0 = 2 * t;
    #pragma unroll
    for (int d = 0; d < ND; ++d) {
        if (d > w0)     res0[d] = lsum0;
        if (d > w0 + 1) res1[d] = lsum1;
    }

    float4* op = reinterpret_cast<float4*>(out + pix0 * ND);
    op[0] = make_float4(res0[0], res0[1], res0[2],  res0[3]);
    op[1] = make_float4(res0[4], res0[5], res0[6],  res0[7]);
    op[2] = make_float4(res0[8], res0[9], res0[10], res0[11]);
    op[3] = make_float4(res1[0], res1[1], res1[2],  res1[3]);
    op[4] = make_float4(res1[4], res1[5], res1[6],  res1[7]);
    op[5] = make_float4(res1[8], res1[9], res1[10], res1[11]);
}

extern "C" void kernel_launch(void* const* d_in, const int* in_sizes, int n_in,
                              void* d_out, int out_size, void* d_ws, size_t ws_size,
                              hipStream_t stream)
{
    const float* fl = (const float*)d_in[0];
    const float* fr = (const float*)d_in[1];
    float* out = (float*)d_out;

    const int grid = 8 * 256;                // one block per (b, h) row
    cost_volume_kernel<<<grid, 256, 0, stream>>>(fl, fr, out);
}

// Round 4
// 101.570 us; speedup vs baseline: 1.2294x; 1.2294x over previous
//
#include <hip/hip_runtime.h>

// CostVolume2D: B=8, H=256, W=512, C=32, n_disp=12, stride=1.
// cost[b,h,w,d] = sum_c |feat_l[b,h,w,c] - feat_r[b,h,w-d,c]|, feat_r zero-padded left.
//
// Block = 256 threads = half a row, 1 pixel/thread.
// feat_r tile (267 cols x 32ch) staged in LDS as plane-major SoA:
//   lds[q][colr], q = float4-quarter (0..7), colr = col - (wstart-11) in [0,266].
//   NCOL = 273 (== 1 mod 8):
//     reads  at fixed (q,d): chunk = q*273 + t + (11-d) -> lanes consecutive,
//            conflict-free, 12 reads share one base + imm offsets.
//     writes (reg-staged): 8-lane group covers all 8 bank quads (273 % 8 == 1).
// Staging global loads: lane runs are 64 consecutive float4s -> 1024 B coalesced.

constexpr int Wd   = 512;
constexpr int ND   = 12;
constexpr int NCOL = 273;             // 267 + pad, == 1 mod 8
constexpr int NCHUNK = 8 * NCOL;      // 2184 chunks = 34944 B
constexpr int NSRC = 267 * 8;         // 2136 source chunks per tile

__device__ __forceinline__ float l1_4(float4 a, float4 b) {
    return fabsf(a.x - b.x) + fabsf(a.y - b.y) + fabsf(a.z - b.z) + fabsf(a.w - b.w);
}

__global__ __launch_bounds__(256, 4) void cost_volume_kernel(
    const float* __restrict__ fl,
    const float* __restrict__ fr,
    float* __restrict__ out)
{
    __shared__ float4 lds4[NCHUNK];

    const int t    = threadIdx.x;
    const int wave = t >> 6;
    const int lane = t & 63;
    const int wstart = (blockIdx.x & 1) * 256;
    const int bh     = blockIdx.x >> 1;            // b*H + h
    const float4* fr_row4 = reinterpret_cast<const float4*>(fr + (size_t)bh * Wd * 32);

    // ---- stage: coalesced global loads into registers
    float4 streg[9];
    #pragma unroll
    for (int it = 0; it < 9; ++it) {
        const int r = it * 4 + wave;
        if (r < 34) {
            const int ss   = min(r * 64 + lane, NSRC - 1);   // clamp tail
            const int colr = ss >> 3;
            const int q    = ss & 7;
            int col = wstart - 11 + colr;
            col = max(col, 0);                    // left-edge clamp; content don't-care
            streg[it] = fr_row4[col * 8 + q];
        }
    }

    // ---- feat_l[b,h,w,:] into registers (overlaps with staging loads)
    const int w = wstart + t;
    const size_t pix = (size_t)bh * Wd + w;
    const float4* lp = reinterpret_cast<const float4*>(fl) + pix * 8;
    float4 L[8];
    #pragma unroll
    for (int q = 0; q < 8; ++q) L[q] = lp[q];

    float lsum = 0.f;
    #pragma unroll
    for (int q = 0; q < 8; ++q)
        lsum += fabsf(L[q].x) + fabsf(L[q].y) + fabsf(L[q].z) + fabsf(L[q].w);

    // ---- permuted ds_writes (balanced across bank quads)
    #pragma unroll
    for (int it = 0; it < 9; ++it) {
        const int r = it * 4 + wave;
        if (r < 34) {
            const int ss   = min(r * 64 + lane, NSRC - 1);
            const int colr = ss >> 3;
            const int q    = ss & 7;
            lds4[q * NCOL + colr] = streg[it];
        }
    }

    __syncthreads();

    // ---- 12 disparities from LDS: per q one base, 12 imm-offset ds_read_b128
    float res[ND];
    #pragma unroll
    for (int d = 0; d < ND; ++d) res[d] = 0.f;

    #pragma unroll
    for (int q = 0; q < 8; ++q) {
        const float4 Lq = L[q];
        const float4* base = &lds4[q * NCOL + t];   // colr = t + (11-d)
        #pragma unroll
        for (int d = 0; d < ND; ++d) {
            res[d] += l1_4(Lq, base[11 - d]);
        }
    }

    // ---- left edge: w < d -> feat_r fully shifted out (zeros) -> sum|feat_l|
    #pragma unroll
    for (int d = 0; d < ND; ++d)
        if (w < d) res[d] = lsum;

    float4* op = reinterpret_cast<float4*>(out + pix * ND);
    op[0] = make_float4(res[0], res[1], res[2],  res[3]);
    op[1] = make_float4(res[4], res[5], res[6],  res[7]);
    op[2] = make_float4(res[8], res[9], res[10], res[11]);
}

extern "C" void kernel_launch(void* const* d_in, const int* in_sizes, int n_in,
                              void* d_out, int out_size, void* d_ws, size_t ws_size,
                              hipStream_t stream)
{
    const float* fl = (const float*)d_in[0];
    const float* fr = (const float*)d_in[1];
    float* out = (float*)d_out;

    const int grid = 8 * 256 * 2;                // (b,h) x 2 half-rows
    cost_volume_kernel<<<grid, 256, 0, stream>>>(fl, fr, out);
}